// Round 1
// baseline (131.810 us; speedup 1.0000x reference)
//
#include <hip/hip_runtime.h>
#include <hip/hip_bf16.h>
#include <math.h>

// DeformConv2D MI355X: b=4,c=64,H=W=128,KS=3,N=9 -> out[b,o,h,w] = sum_{c,n} W[o,c,n]*bilin(xpad,p)
// R9: fuse offset_setup + gather_mfma into one kernel. cpk/cwt handoff moves from global
//     (11.8 MB write + 11.8 MB read + extra 2048-block launch) into 5.76 KB of LDS.
//     Gx..Gw products hoisted from per-lane gather into per-item P3 (same fp32 ops/order).
//     Numerics bit-identical (absmax 0.03125). LDS 42,880 B -> 3 blocks/CU.

typedef __attribute__((ext_vector_type(8)))  short short8;
typedef __attribute__((ext_vector_type(4)))  short short4_t;
typedef __attribute__((ext_vector_type(16))) float float16;

#define NPIX 65536
#define XS_STRIDE 580   // xs leading dim (bf16): dword stride 290 = 2 mod 32 -> 2-way (free)
#define K2_WS 68        // stage wp stride (64ch + 4 pad)
#define K2_RS 2312      // stage row stride (34*68)

// workspace layout (byte offsets)
#define XPB_B   0u           // bf16 hi padded NHWC x : 8,652,800 B
#define XPL_B   8652800u     // bf16 lo residual      : 8,652,800 B
#define WBB_B   17305600u    // W_conv bf16 MFMA B-frags: 73,728 B
#define WOH_B   17379328u    // W_off hi B-frags      : 36,864 B
#define WOL_B   17416192u    // W_off lo B-frags      : 36,864 B (end 17,453,056)

__device__ inline unsigned short f2bf(float f) {
    unsigned int u = __float_as_uint(f);
    u += 0x7fffu + ((u >> 16) & 1u);           // RNE
    return (unsigned short)(u >> 16);
}
__device__ inline float bfhi2f(unsigned int v) { return __uint_as_float(v & 0xffff0000u); }
__device__ inline float bflo2f(unsigned int v) { return __uint_as_float(v << 16); }

// ---------------------------------------------------------------- K1: pad/transpose + weight prep
__global__ __launch_bounds__(1024) void pad_prep(const float* __restrict__ x,
                                                 const float* __restrict__ W_off,
                                                 const float* __restrict__ W_conv,
                                                 char* __restrict__ wsb) {
    unsigned short* xpb = (unsigned short*)(wsb + XPB_B);
    unsigned short* xpl = (unsigned short*)(wsb + XPL_B);
    int t = threadIdx.x;
    if (blockIdx.x >= 520) {   // ---- weight prep: 16 blocks x 3456 items
        unsigned short* Wb  = (unsigned short*)(wsb + WBB_B);
        unsigned short* Woh = (unsigned short*)(wsb + WOH_B);
        unsigned short* Wol = (unsigned short*)(wsb + WOL_B);
        int wb = blockIdx.x - 520;
        for (int ii = t; ii < 3456; ii += 1024) {
            int e = wb * 3456 + ii;
            if (e < 36864) {
                int j = e & 7, lane = (e >> 3) & 63, t2 = e >> 9;
                int ks = t2 % 36, nt = t2 / 36;
                int k = ks * 16 + ((lane >> 5) << 3) + j;
                int n = nt * 32 + (lane & 31);
                Wb[e] = f2bf(W_conv[(n * 64 + (k & 63)) * 9 + (k >> 6)]);
            } else {
                int e2 = e - 36864;     // W_off hi/lo frags, N=32 (18 used)
                int j = e2 & 7, lane = (e2 >> 3) & 63, ksg = e2 >> 9;
                int k = ksg * 16 + ((lane >> 5) << 3) + j;
                int c = k & 63, tap = k >> 6, n = lane & 31;
                float v = 0.f;
                if (n < 18) { int ko = (n < 9) ? 2 * n : 2 * (n - 9) + 1; v = W_off[(ko * 64 + c) * 9 + tap]; }
                unsigned short hi = f2bf(v);
                Woh[e2] = hi;
                Wol[e2] = f2bf(v - bfhi2f((unsigned int)hi << 16));
            }
        }
        return;
    }
    __shared__ float tile[64][129];
    int hp = blockIdx.x % 130, b = blockIdx.x / 130;
    int rowbase = ((b * 130 + hp) * 130) * 64;
    if (hp == 0 || hp == 129) {
        for (int i = t; i < 130 * 32; i += 1024) {
            ((unsigned*)(xpb + rowbase))[i] = 0u;
            ((unsigned*)(xpl + rowbase))[i] = 0u;
        }
        return;
    }
    int h = hp - 1;
    {
        int w = t & 127, cq = t >> 7;
#pragma unroll
        for (int cc = 0; cc < 8; cc++) {
            int c = cq + cc * 8;
            tile[c][w] = x[(((b * 64 + c) * 128) + h) * 128 + w];   // coalesced over w
        }
    }
    __syncthreads();
    {
        int c2 = (t & 31) * 2, wq = t >> 5;
        if (wq == 0) { ((unsigned*)(xpb + rowbase))[t & 31] = 0u; ((unsigned*)(xpl + rowbase))[t & 31] = 0u; }
        if (wq == 1) { ((unsigned*)(xpb + rowbase + 129 * 64))[t & 31] = 0u; ((unsigned*)(xpl + rowbase + 129 * 64))[t & 31] = 0u; }
#pragma unroll
        for (int w = wq; w < 128; w += 32) {
            float v0 = tile[c2][w], v1 = tile[c2 + 1][w];
            unsigned short h0 = f2bf(v0), h1 = f2bf(v1);
            unsigned short l0 = f2bf(v0 - bfhi2f((unsigned int)h0 << 16));
            unsigned short l1 = f2bf(v1 - bfhi2f((unsigned int)h1 << 16));
            int ad = (rowbase + (w + 1) * 64) / 2 + (t & 31);
            ((unsigned*)xpb)[ad] = (unsigned)h0 | ((unsigned)h1 << 16);
            ((unsigned*)xpl)[ad] = (unsigned)l0 | ((unsigned)l1 << 16);
        }
    }
}

// ---------------------------------------------------------------- K2: fused offset conv + bilinear
// setup + gather + contraction MFMA. block = 256 thr (4 waves), 32 pixels.
// Phases: P0 stage 3x34x64 hi/lo -> P1 27 split-bf16 MFMA -> P2 obuf -> P3 bilinear setup ->
//         cdat (LDS) -> P5 gather -> xs -> P6 contraction MFMA -> P7 combine -> out.
// LDS: [0,37120) xs (aliases stage 27,744 / obuf 9,728 / obuf2 16,896), [37120,42880) cdat.
__global__ __launch_bounds__(256) void deform_fused(const float* __restrict__ b_off,
                                                    float* __restrict__ out,
                                                    char* __restrict__ wsb) {
    const unsigned* xpbw = (const unsigned*)(wsb + XPB_B);
    const unsigned* xplw = (const unsigned*)(wsb + XPL_B);
    const short8* Woh = (const short8*)(wsb + WOH_B);
    const short8* Wol = (const short8*)(wsb + WOL_B);
    const short8* Wb  = (const short8*)(wsb + WBB_B);

    __shared__ __attribute__((aligned(16))) char smem[42880];
    unsigned short* xh = (unsigned short*)smem;              // stage hi: 3*2312 (13,872 B)
    unsigned short* xl = xh + 3 * K2_RS;                     // stage lo (ends 27,744)
    float* obuf = (float*)smem;                              // [4][32][19] = 9,728 B (after B2)
    unsigned short* xs = (unsigned short*)smem;              // [32][580] = 37,120 B (after B4)
    unsigned* cpkL = (unsigned*)(smem + 37120);              // 288 u32 = 1,152 B
    float4*   cwtL = (float4*)(smem + 37120 + 1152);         // 288 float4 = 4,608 B (end 42,880)
    float* obuf2 = (float*)smem;                             // [4][32][33] = 16,896 B (after B6)

    int t = threadIdx.x;
    int lane = t & 63, wv = t >> 6;
    int pixbase = blockIdx.x * 32;
    int w0 = pixbase & 127, h0 = (pixbase >> 7) & 127, bimg = pixbase >> 14;
    int m = lane & 31, half8 = (lane >> 5) << 3;

    // ---- P0: stage 3 rows x 34 cols x 64 ch hi/lo (dword = 2ch), fully coalesced
    for (int i = t; i < 3264; i += 256) {
        int row = i / 1088, rem = i - row * 1088;
        int wp = rem >> 5, cd = rem & 31;
        int g = ((bimg * 130 + h0 + row) * 130 + (w0 + wp)) * 32 + cd;
        int d = row * (K2_RS / 2) + wp * (K2_WS / 2) + cd;
        ((unsigned*)xh)[d] = xpbw[g];
        ((unsigned*)xl)[d] = xplw[g];
    }
    __syncthreads();                                         // B1

    // ---- P1: offset conv via split-bf16 MFMA (M=32 px, N=32 (18 used), K=576/4 per wave)
    {
        float16 acc;
#pragma unroll
        for (int r = 0; r < 16; r++) acc[r] = 0.f;
#pragma unroll
        for (int i = 0; i < 9; i++) {
            int ksg = wv * 9 + i;
            int tap = ksg >> 2;
            int c0 = ((ksg & 3) << 4) + half8;
            int ty = tap / 3, tx = tap - 3 * ty;
            int eb = ty * K2_RS + (m + tx) * K2_WS + c0;
            short4_t h0v = *(const short4_t*)(xh + eb);
            short4_t h1v = *(const short4_t*)(xh + eb + 4);
            short4_t l0v = *(const short4_t*)(xl + eb);
            short4_t l1v = *(const short4_t*)(xl + eb + 4);
            short8 ah = __builtin_shufflevector(h0v, h1v, 0, 1, 2, 3, 4, 5, 6, 7);
            short8 al = __builtin_shufflevector(l0v, l1v, 0, 1, 2, 3, 4, 5, 6, 7);
            short8 bh = Woh[ksg * 64 + lane];
            short8 bl = Wol[ksg * 64 + lane];
            acc = __builtin_amdgcn_mfma_f32_32x32x16_bf16(ah, bh, acc, 0, 0, 0);
            acc = __builtin_amdgcn_mfma_f32_32x32x16_bf16(ah, bl, acc, 0, 0, 0);
            acc = __builtin_amdgcn_mfma_f32_32x32x16_bf16(al, bh, acc, 0, 0, 0);
        }
        __syncthreads();                                     // B2: stage reads done, obuf fresh
        // ---- P2: partials -> obuf[wv][row][n] (n<18 used, stride 19)
        if (m < 18) {
#pragma unroll
            for (int r = 0; r < 16; r++) {
                int row = (r & 3) + 8 * (r >> 2) + 4 * (lane >> 5);
                obuf[(wv * 32 + row) * 19 + m] = acc[r];
            }
        }
    }
    __syncthreads();                                         // B3

    // ---- P3: per-(pixel,tap) bilinear setup (exact fp32 decisions) -> cdat in LDS
#pragma unroll
    for (int s = 0; s < 2; s++) {
        if (s == 1 && t >= 32) break;
        int it = t + s * 256;
        int p = (it * 7282) >> 16;              // /9
        int n = it - p * 9;
        float orow = b_off[2 * n], ocol = b_off[2 * n + 1];
#pragma unroll
        for (int kq = 0; kq < 4; kq++) {
            orow += obuf[(kq * 32 + p) * 19 + n];
            ocol += obuf[(kq * 32 + p) * 19 + 9 + n];
        }
        float pr = (float)(h0 + (n / 3)) + orow;
        float pc = (float)(w0 + p + (n % 3)) + ocol;
        float flr = floorf(pr), flc = floorf(pc);
        float qlt_r = fminf(fmaxf(flr, 0.f), 129.f);
        float qlt_c = fminf(fmaxf(flc, 0.f), 129.f);
        float qrb_r = fminf(fmaxf(flr + 1.f, 0.f), 129.f);
        float qrb_c = fminf(fmaxf(flc + 1.f, 0.f), 129.f);
        bool mr = (pr < 1.f) || (pr > 128.f);
        bool mc = (pc < 1.f) || (pc > 128.f);
        float pr2 = mr ? flr : pr; pr2 = fminf(fmaxf(pr2, 0.f), 129.f);
        float pc2 = mc ? flc : pc; pc2 = fminf(fmaxf(pc2, 0.f), 129.f);
        float wr_lt = 1.f + (qlt_r - pr2);
        float wr_rb = 1.f - (qrb_r - pr2);
        float wc_lt = 1.f + (qlt_c - pc2);
        float wc_rb = 1.f - (qrb_c - pc2);
        int ilt_r = (int)qlt_r, ilt_c = (int)qlt_c;
        int irb_r = (int)qrb_r, irb_c = (int)qrb_c;
        // Gx..Gw hoisted from gather lanes (same fp32 mults, same operand order)
        float Gx = wr_lt * wc_lt, Gy = wr_rb * wc_rb;
        float Gz = wr_lt * wc_rb, Gw = wr_rb * wc_lt;
        cpkL[it] = (unsigned)ilt_r | ((unsigned)ilt_c << 8)
                 | ((unsigned)irb_r << 16) | ((unsigned)irb_c << 24);
        cwtL[it] = make_float4(Gx, Gy, Gz, Gw);
    }
    __syncthreads();                                         // B4: obuf reads done -> xs fresh; cdat visible

    // ---- P5: gather (2 items/wave-load, half-wave per item; 128B coalesced corner rows)
    {
        int half = lane >> 5;
        int cp4 = (lane & 31) * 4;
        const char* bp = (const char*)(wsb + XPB_B) + (size_t)bimg * (130 * 130 * 128);
        char* xsb = (char*)xs;
        int baseL = wv * 72;
        int n5 = half;
        int sa = wv * 8 * (XS_STRIDE * 2) + n5 * 128;
#pragma unroll 4
        for (int i = 0; i < 36; i++) {
            int item = baseL + 2 * i + half;
            unsigned pk = cpkL[item];                        // uniform per half-wave, LDS broadcast
            float4 wt = cwtL[item];
            int rlt = pk & 255, clt = (pk >> 8) & 255, rrb = (pk >> 16) & 255, crb = pk >> 24;
            int aLT = rlt * 16640 + clt * 128;
            int aRB = rrb * 16640 + crb * 128;
            int aLB = rlt * 16640 + crb * 128;
            int aRT = rrb * 16640 + clt * 128;
            unsigned int vlt = *(const unsigned int*)(bp + aLT + cp4);
            unsigned int vrb = *(const unsigned int*)(bp + aRB + cp4);
            unsigned int vlb = *(const unsigned int*)(bp + aLB + cp4);
            unsigned int vrt = *(const unsigned int*)(bp + aRT + cp4);
            float lo = fmaf(wt.x, bflo2f(vlt), fmaf(wt.y, bflo2f(vrb), fmaf(wt.z, bflo2f(vlb), wt.w * bflo2f(vrt))));
            float hi = fmaf(wt.x, bfhi2f(vlt), fmaf(wt.y, bfhi2f(vrb), fmaf(wt.z, bfhi2f(vlb), wt.w * bfhi2f(vrt))));
            __hip_bfloat162 pk2 = __float22bfloat162_rn(make_float2(lo, hi));
            *(unsigned int*)(xsb + sa + cp4) = *(unsigned int*)&pk2;
            n5 += 2; sa += 256;
            if (n5 >= 9) { n5 -= 9; sa += 8; }   // (p+1, n-9)
        }
    }
    __syncthreads();                                         // B5

    // ---- P6: contraction MFMA. wave: nt = N-tile (32 outs), kh = K-half (288)
    int nt = wv & 1, kh = wv >> 1;
    float16 acc;
#pragma unroll
    for (int r = 0; r < 16; r++) acc[r] = 0.f;
    for (int i2 = 0; i2 < 18; i2++) {
        int ksg = kh * 18 + i2;
        int baseE = m * XS_STRIDE + ksg * 16 + half8;
        short4_t a0 = *(const short4_t*)(xs + baseE);        // b64: stride 290dw -> 2-way only
        short4_t a1 = *(const short4_t*)(xs + baseE + 4);
        short8 af = __builtin_shufflevector(a0, a1, 0, 1, 2, 3, 4, 5, 6, 7);
        short8 bfv = Wb[(nt * 36 + ksg) * 64 + lane];        // coalesced 1KB, L2-resident
        acc = __builtin_amdgcn_mfma_f32_32x32x16_bf16(af, bfv, acc, 0, 0, 0);
    }
    __syncthreads();                                         // B6: all xs reads done -> obuf2 alias safe
    // ---- P7: each (kh,nt) wave writes its own obuf2 region; single barrier; add at store
#pragma unroll
    for (int r = 0; r < 16; r++) {
        int mrow = (r & 3) + 8 * (r >> 2) + 4 * (lane >> 5);
        obuf2[(kh * 2 + nt) * 1056 + mrow * 33 + m] = acc[r];
    }
    __syncthreads();                                         // B7
#pragma unroll
    for (int i = 0; i < 8; i++) {
        int lin = i * 256 + t;
        int o = lin >> 5, p = lin & 31;
        int oi = (o >> 5) * 1056 + p * 33 + (o & 31);
        float v = obuf2[oi] + obuf2[oi + 2112];   // acc_kh0 + acc_kh1
        out[((bimg * 64 + o) << 14) + (h0 << 7) + w0 + p] = v;
    }
}

// ---------------------------------------------------------------- launch
extern "C" void kernel_launch(void* const* d_in, const int* in_sizes, int n_in,
                              void* d_out, int out_size, void* d_ws, size_t ws_size,
                              hipStream_t stream) {
    const float* x      = (const float*)d_in[0];
    const float* W_off  = (const float*)d_in[1];
    const float* b_off  = (const float*)d_in[2];
    const float* W_conv = (const float*)d_in[3];
    char* wsb  = (char*)d_ws;            // needs 17,453,056 B
    float* out = (float*)d_out;

    hipLaunchKernelGGL(pad_prep, dim3(536), dim3(1024), 0, stream, x, W_off, W_conv, wsb);
    hipLaunchKernelGGL(deform_fused, dim3(NPIX / 32), dim3(256), 0, stream, b_off, out, wsb);
}

// Round 2
// 121.619 us; speedup vs baseline: 1.0838x; 1.0838x over previous
//
#include <hip/hip_runtime.h>
#include <hip/hip_bf16.h>
#include <math.h>

// DeformConv2D MI355X: b=4,c=64,H=W=128,KS=3,N=9 -> out[b,o,h,w] = sum_{c,n} W[o,c,n]*bilin(xpad,p)
// R10: deform_fused 256 -> 512 threads (8 waves), same 32-px tile + 43KB LDS.
//      LDS still limits to 3 blocks/CU, but waves/CU double: 12 -> 24 (6/SIMD).
//      Per-wave serial work halves: stage 7 iters, gather 18 iters/wave, contraction 9 MFMA/wave
//      (K split in quarters, 8 obuf2 partials). Offset conv (P1/P2/P3) unchanged on waves 0-3
//      -> bilinear floor() decisions bit-identical; only kh-partial sum order changes (ulp-level).

typedef __attribute__((ext_vector_type(8)))  short short8;
typedef __attribute__((ext_vector_type(4)))  short short4_t;
typedef __attribute__((ext_vector_type(16))) float float16;

#define NPIX 65536
#define XS_STRIDE 580   // xs leading dim (bf16): dword stride 290 = 2 mod 32 -> 2-way (free)
#define K2_WS 68        // stage wp stride (64ch + 4 pad)
#define K2_RS 2312      // stage row stride (34*68)

// workspace layout (byte offsets)
#define XPB_B   0u           // bf16 hi padded NHWC x : 8,652,800 B
#define XPL_B   8652800u     // bf16 lo residual      : 8,652,800 B
#define WBB_B   17305600u    // W_conv bf16 MFMA B-frags: 73,728 B
#define WOH_B   17379328u    // W_off hi B-frags      : 36,864 B
#define WOL_B   17416192u    // W_off lo B-frags      : 36,864 B (end 17,453,056)

__device__ inline unsigned short f2bf(float f) {
    unsigned int u = __float_as_uint(f);
    u += 0x7fffu + ((u >> 16) & 1u);           // RNE
    return (unsigned short)(u >> 16);
}
__device__ inline float bfhi2f(unsigned int v) { return __uint_as_float(v & 0xffff0000u); }
__device__ inline float bflo2f(unsigned int v) { return __uint_as_float(v << 16); }

// ---------------------------------------------------------------- K1: pad/transpose + weight prep
__global__ __launch_bounds__(1024) void pad_prep(const float* __restrict__ x,
                                                 const float* __restrict__ W_off,
                                                 const float* __restrict__ W_conv,
                                                 char* __restrict__ wsb) {
    unsigned short* xpb = (unsigned short*)(wsb + XPB_B);
    unsigned short* xpl = (unsigned short*)(wsb + XPL_B);
    int t = threadIdx.x;
    if (blockIdx.x >= 520) {   // ---- weight prep: 16 blocks x 3456 items
        unsigned short* Wb  = (unsigned short*)(wsb + WBB_B);
        unsigned short* Woh = (unsigned short*)(wsb + WOH_B);
        unsigned short* Wol = (unsigned short*)(wsb + WOL_B);
        int wb = blockIdx.x - 520;
        for (int ii = t; ii < 3456; ii += 1024) {
            int e = wb * 3456 + ii;
            if (e < 36864) {
                int j = e & 7, lane = (e >> 3) & 63, t2 = e >> 9;
                int ks = t2 % 36, nt = t2 / 36;
                int k = ks * 16 + ((lane >> 5) << 3) + j;
                int n = nt * 32 + (lane & 31);
                Wb[e] = f2bf(W_conv[(n * 64 + (k & 63)) * 9 + (k >> 6)]);
            } else {
                int e2 = e - 36864;     // W_off hi/lo frags, N=32 (18 used)
                int j = e2 & 7, lane = (e2 >> 3) & 63, ksg = e2 >> 9;
                int k = ksg * 16 + ((lane >> 5) << 3) + j;
                int c = k & 63, tap = k >> 6, n = lane & 31;
                float v = 0.f;
                if (n < 18) { int ko = (n < 9) ? 2 * n : 2 * (n - 9) + 1; v = W_off[(ko * 64 + c) * 9 + tap]; }
                unsigned short hi = f2bf(v);
                Woh[e2] = hi;
                Wol[e2] = f2bf(v - bfhi2f((unsigned int)hi << 16));
            }
        }
        return;
    }
    __shared__ float tile[64][129];
    int hp = blockIdx.x % 130, b = blockIdx.x / 130;
    int rowbase = ((b * 130 + hp) * 130) * 64;
    if (hp == 0 || hp == 129) {
        for (int i = t; i < 130 * 32; i += 1024) {
            ((unsigned*)(xpb + rowbase))[i] = 0u;
            ((unsigned*)(xpl + rowbase))[i] = 0u;
        }
        return;
    }
    int h = hp - 1;
    {
        int w = t & 127, cq = t >> 7;
#pragma unroll
        for (int cc = 0; cc < 8; cc++) {
            int c = cq + cc * 8;
            tile[c][w] = x[(((b * 64 + c) * 128) + h) * 128 + w];   // coalesced over w
        }
    }
    __syncthreads();
    {
        int c2 = (t & 31) * 2, wq = t >> 5;
        if (wq == 0) { ((unsigned*)(xpb + rowbase))[t & 31] = 0u; ((unsigned*)(xpl + rowbase))[t & 31] = 0u; }
        if (wq == 1) { ((unsigned*)(xpb + rowbase + 129 * 64))[t & 31] = 0u; ((unsigned*)(xpl + rowbase + 129 * 64))[t & 31] = 0u; }
#pragma unroll
        for (int w = wq; w < 128; w += 32) {
            float v0 = tile[c2][w], v1 = tile[c2 + 1][w];
            unsigned short h0 = f2bf(v0), h1 = f2bf(v1);
            unsigned short l0 = f2bf(v0 - bfhi2f((unsigned int)h0 << 16));
            unsigned short l1 = f2bf(v1 - bfhi2f((unsigned int)h1 << 16));
            int ad = (rowbase + (w + 1) * 64) / 2 + (t & 31);
            ((unsigned*)xpb)[ad] = (unsigned)h0 | ((unsigned)h1 << 16);
            ((unsigned*)xpl)[ad] = (unsigned)l0 | ((unsigned)l1 << 16);
        }
    }
}

// ---------------------------------------------------------------- K2: fused, 8 waves / 32 px
// Phases: P0 stage (all waves) -> P1 offset MFMA (waves 0-3, identical to R9) -> P2 obuf ->
//         P3 bilinear setup (t<288) -> P5 gather (8 waves x 36 items) ->
//         P6 contraction MFMA (kh 0..3 x nt 0..1) -> P7 combine 4 kh partials -> out.
// LDS: [0,37120) xs (aliases stage 27,744 / obuf 9,728 / obuf2 33,792), [37120,42880) cdat.
__global__ __launch_bounds__(512, 6) void deform_fused(const float* __restrict__ b_off,
                                                       float* __restrict__ out,
                                                       char* __restrict__ wsb) {
    const unsigned* xpbw = (const unsigned*)(wsb + XPB_B);
    const unsigned* xplw = (const unsigned*)(wsb + XPL_B);
    const short8* Woh = (const short8*)(wsb + WOH_B);
    const short8* Wol = (const short8*)(wsb + WOL_B);
    const short8* Wb  = (const short8*)(wsb + WBB_B);

    __shared__ __attribute__((aligned(16))) char smem[42880];
    unsigned short* xh = (unsigned short*)smem;              // stage hi: 3*2312 (13,872 B)
    unsigned short* xl = xh + 3 * K2_RS;                     // stage lo (ends 27,744)
    float* obuf = (float*)smem;                              // [4][32][19] = 9,728 B (after B2)
    unsigned short* xs = (unsigned short*)smem;              // [32][580] = 37,120 B (after B4)
    unsigned* cpkL = (unsigned*)(smem + 37120);              // 288 u32 = 1,152 B
    float4*   cwtL = (float4*)(smem + 37120 + 1152);         // 288 float4 = 4,608 B (end 42,880)
    float* obuf2 = (float*)smem;                             // [8][32][33] = 33,792 B (after B6)

    int t = threadIdx.x;
    int lane = t & 63, wv = t >> 6;                          // wv 0..7
    int pixbase = blockIdx.x * 32;
    int w0 = pixbase & 127, h0 = (pixbase >> 7) & 127, bimg = pixbase >> 14;
    int m = lane & 31, half8 = (lane >> 5) << 3;

    // ---- P0: stage 3 rows x 34 cols x 64 ch hi/lo (dword = 2ch), fully coalesced
    for (int i = t; i < 3264; i += 512) {
        int row = i / 1088, rem = i - row * 1088;
        int wp = rem >> 5, cd = rem & 31;
        int g = ((bimg * 130 + h0 + row) * 130 + (w0 + wp)) * 32 + cd;
        int d = row * (K2_RS / 2) + wp * (K2_WS / 2) + cd;
        ((unsigned*)xh)[d] = xpbw[g];
        ((unsigned*)xl)[d] = xplw[g];
    }
    __syncthreads();                                         // B1

    // ---- P1: offset conv via split-bf16 MFMA, waves 0-3 (identical grouping to R9)
    float16 acc1;
#pragma unroll
    for (int r = 0; r < 16; r++) acc1[r] = 0.f;
    if (wv < 4) {
#pragma unroll
        for (int i = 0; i < 9; i++) {
            int ksg = wv * 9 + i;
            int tap = ksg >> 2;
            int c0 = ((ksg & 3) << 4) + half8;
            int ty = tap / 3, tx = tap - 3 * ty;
            int eb = ty * K2_RS + (m + tx) * K2_WS + c0;
            short4_t h0v = *(const short4_t*)(xh + eb);
            short4_t h1v = *(const short4_t*)(xh + eb + 4);
            short4_t l0v = *(const short4_t*)(xl + eb);
            short4_t l1v = *(const short4_t*)(xl + eb + 4);
            short8 ah = __builtin_shufflevector(h0v, h1v, 0, 1, 2, 3, 4, 5, 6, 7);
            short8 al = __builtin_shufflevector(l0v, l1v, 0, 1, 2, 3, 4, 5, 6, 7);
            short8 bh = Woh[ksg * 64 + lane];
            short8 bl = Wol[ksg * 64 + lane];
            acc1 = __builtin_amdgcn_mfma_f32_32x32x16_bf16(ah, bh, acc1, 0, 0, 0);
            acc1 = __builtin_amdgcn_mfma_f32_32x32x16_bf16(ah, bl, acc1, 0, 0, 0);
            acc1 = __builtin_amdgcn_mfma_f32_32x32x16_bf16(al, bh, acc1, 0, 0, 0);
        }
    }
    __syncthreads();                                         // B2: stage reads done, obuf fresh
    // ---- P2: partials -> obuf[wv][row][n] (waves 0-3, n<18 used, stride 19)
    if (wv < 4 && m < 18) {
#pragma unroll
        for (int r = 0; r < 16; r++) {
            int row = (r & 3) + 8 * (r >> 2) + 4 * (lane >> 5);
            obuf[(wv * 32 + row) * 19 + m] = acc1[r];
        }
    }
    __syncthreads();                                         // B3

    // ---- P3: per-(pixel,tap) bilinear setup (exact fp32 decisions, identical to R9) -> cdat LDS
    if (t < 288) {
        int it = t;
        int p = (it * 7282) >> 16;              // /9
        int n = it - p * 9;
        float orow = b_off[2 * n], ocol = b_off[2 * n + 1];
#pragma unroll
        for (int kq = 0; kq < 4; kq++) {
            orow += obuf[(kq * 32 + p) * 19 + n];
            ocol += obuf[(kq * 32 + p) * 19 + 9 + n];
        }
        float pr = (float)(h0 + (n / 3)) + orow;
        float pc = (float)(w0 + p + (n % 3)) + ocol;
        float flr = floorf(pr), flc = floorf(pc);
        float qlt_r = fminf(fmaxf(flr, 0.f), 129.f);
        float qlt_c = fminf(fmaxf(flc, 0.f), 129.f);
        float qrb_r = fminf(fmaxf(flr + 1.f, 0.f), 129.f);
        float qrb_c = fminf(fmaxf(flc + 1.f, 0.f), 129.f);
        bool mr = (pr < 1.f) || (pr > 128.f);
        bool mc = (pc < 1.f) || (pc > 128.f);
        float pr2 = mr ? flr : pr; pr2 = fminf(fmaxf(pr2, 0.f), 129.f);
        float pc2 = mc ? flc : pc; pc2 = fminf(fmaxf(pc2, 0.f), 129.f);
        float wr_lt = 1.f + (qlt_r - pr2);
        float wr_rb = 1.f - (qrb_r - pr2);
        float wc_lt = 1.f + (qlt_c - pc2);
        float wc_rb = 1.f - (qrb_c - pc2);
        int ilt_r = (int)qlt_r, ilt_c = (int)qlt_c;
        int irb_r = (int)qrb_r, irb_c = (int)qrb_c;
        float Gx = wr_lt * wc_lt, Gy = wr_rb * wc_rb;
        float Gz = wr_lt * wc_rb, Gw = wr_rb * wc_lt;
        cpkL[it] = (unsigned)ilt_r | ((unsigned)ilt_c << 8)
                 | ((unsigned)irb_r << 16) | ((unsigned)irb_c << 24);
        cwtL[it] = make_float4(Gx, Gy, Gz, Gw);
    }
    __syncthreads();                                         // B4: obuf reads done -> xs fresh; cdat visible

    // ---- P5: gather, 8 waves x 36 items (2 items/wave-iter, half-wave per item)
    {
        int half = lane >> 5;
        int cp4 = (lane & 31) * 4;
        const char* bp = (const char*)(wsb + XPB_B) + (size_t)bimg * (130 * 130 * 128);
        char* xsb = (char*)xs;
        int baseL = wv * 36;                                 // pixels [4wv, 4wv+4)
        int n5 = half;
        int sa = wv * 4 * (XS_STRIDE * 2) + n5 * 128;
#pragma unroll 4
        for (int i = 0; i < 18; i++) {
            int item = baseL + 2 * i + half;
            unsigned pk = cpkL[item];                        // uniform per half-wave, LDS broadcast
            float4 wt = cwtL[item];
            int rlt = pk & 255, clt = (pk >> 8) & 255, rrb = (pk >> 16) & 255, crb = pk >> 24;
            int aLT = rlt * 16640 + clt * 128;
            int aRB = rrb * 16640 + crb * 128;
            int aLB = rlt * 16640 + crb * 128;
            int aRT = rrb * 16640 + clt * 128;
            unsigned int vlt = *(const unsigned int*)(bp + aLT + cp4);
            unsigned int vrb = *(const unsigned int*)(bp + aRB + cp4);
            unsigned int vlb = *(const unsigned int*)(bp + aLB + cp4);
            unsigned int vrt = *(const unsigned int*)(bp + aRT + cp4);
            float lo = fmaf(wt.x, bflo2f(vlt), fmaf(wt.y, bflo2f(vrb), fmaf(wt.z, bflo2f(vlb), wt.w * bflo2f(vrt))));
            float hi = fmaf(wt.x, bfhi2f(vlt), fmaf(wt.y, bfhi2f(vrb), fmaf(wt.z, bfhi2f(vlb), wt.w * bfhi2f(vrt))));
            __hip_bfloat162 pk2 = __float22bfloat162_rn(make_float2(lo, hi));
            *(unsigned int*)(xsb + sa + cp4) = *(unsigned int*)&pk2;
            n5 += 2; sa += 256;
            if (n5 >= 9) { n5 -= 9; sa += 8; }   // (p+1, n-9)
        }
    }
    __syncthreads();                                         // B5

    // ---- P6: contraction MFMA. wave: nt = N-tile (32 outs), kh = K-quarter (144)
    int nt = wv & 1, kh = wv >> 1;
    float16 acc;
#pragma unroll
    for (int r = 0; r < 16; r++) acc[r] = 0.f;
#pragma unroll
    for (int i2 = 0; i2 < 9; i2++) {
        int ksg = kh * 9 + i2;
        int baseE = m * XS_STRIDE + ksg * 16 + half8;
        short4_t a0 = *(const short4_t*)(xs + baseE);        // b64: stride 290dw -> 2-way only
        short4_t a1 = *(const short4_t*)(xs + baseE + 4);
        short8 af = __builtin_shufflevector(a0, a1, 0, 1, 2, 3, 4, 5, 6, 7);
        short8 bfv = Wb[(nt * 36 + ksg) * 64 + lane];        // coalesced 1KB, L2-resident
        acc = __builtin_amdgcn_mfma_f32_32x32x16_bf16(af, bfv, acc, 0, 0, 0);
    }
    __syncthreads();                                         // B6: all xs reads done -> obuf2 alias safe
    // ---- P7: each (kh,nt) wave writes its own obuf2 region; single barrier; add at store
#pragma unroll
    for (int r = 0; r < 16; r++) {
        int mrow = (r & 3) + 8 * (r >> 2) + 4 * (lane >> 5);
        obuf2[(kh * 2 + nt) * 1056 + mrow * 33 + m] = acc[r];
    }
    __syncthreads();                                         // B7
#pragma unroll
    for (int i = 0; i < 4; i++) {
        int lin = i * 512 + t;
        int o = lin >> 5, p = lin & 31;
        int oi = (o >> 5) * 1056 + p * 33 + (o & 31);
        float v = (obuf2[oi] + obuf2[oi + 2112])
                + (obuf2[oi + 4224] + obuf2[oi + 6336]);     // kh0..kh3 partials
        out[((bimg * 64 + o) << 14) + (h0 << 7) + w0 + p] = v;
    }
}

// ---------------------------------------------------------------- launch
extern "C" void kernel_launch(void* const* d_in, const int* in_sizes, int n_in,
                              void* d_out, int out_size, void* d_ws, size_t ws_size,
                              hipStream_t stream) {
    const float* x      = (const float*)d_in[0];
    const float* W_off  = (const float*)d_in[1];
    const float* b_off  = (const float*)d_in[2];
    const float* W_conv = (const float*)d_in[3];
    char* wsb  = (char*)d_ws;            // needs 17,453,056 B
    float* out = (float*)d_out;

    hipLaunchKernelGGL(pad_prep, dim3(536), dim3(1024), 0, stream, x, W_off, W_conv, wsb);
    hipLaunchKernelGGL(deform_fused, dim3(NPIX / 32), dim3(512), 0, stream, b_off, out, wsb);
}

// Round 3
// 113.153 us; speedup vs baseline: 1.1649x; 1.0748x over previous
//
#include <hip/hip_runtime.h>
#include <hip/hip_bf16.h>
#include <math.h>

// DeformConv2D MI355X: b=4,c=64,H=W=128,KS=3,N=9 -> out[b,o,h,w] = sum_{c,n} W[o,c,n]*bilin(xpad,p)
// R11: occupancy 3 -> 4 blocks/CU by folding cdat into the xs region tail (LDS 42880 -> 37120).
//      cdat records grow to 32B {4 precomputed byte offsets, 4 fp32 weights}; safe because wave wv
//      reads record j at gather-iter floor(j/2) and xs only overwrites the tail at iters 13-17
//      (full cover map verified; same-wave DS ops are program-ordered).
//      P5: saddr loads + imm-offset ds_write (full unroll, zero per-iter address VALU).
//      P1 rebalanced over all 8 waves (5,5,5,5,4,4,4,4 ksg); obuf [8][32][19].
//      fma pairing/nesting identical -> combine bit-identical; partial-sum split ulp-level only.

typedef __attribute__((ext_vector_type(8)))  short short8;
typedef __attribute__((ext_vector_type(4)))  short short4_t;
typedef __attribute__((ext_vector_type(16))) float float16;

#define NPIX 65536
#define XS_STRIDE 580   // xs leading dim (bf16): dword stride 290 = 2 mod 32 -> 2-way (free)
#define K2_WS 68        // stage wp stride (64ch + 4 pad)
#define K2_RS 2312      // stage row stride (34*68)

// workspace layout (byte offsets)
#define XPB_B   0u           // bf16 hi padded NHWC x : 8,652,800 B
#define XPL_B   8652800u     // bf16 lo residual      : 8,652,800 B
#define WBB_B   17305600u    // W_conv bf16 MFMA B-frags: 73,728 B
#define WOH_B   17379328u    // W_off hi B-frags      : 36,864 B
#define WOL_B   17416192u    // W_off lo B-frags      : 36,864 B (end 17,453,056)

__device__ inline unsigned short f2bf(float f) {
    unsigned int u = __float_as_uint(f);
    u += 0x7fffu + ((u >> 16) & 1u);           // RNE
    return (unsigned short)(u >> 16);
}
__device__ inline float bfhi2f(unsigned int v) { return __uint_as_float(v & 0xffff0000u); }
__device__ inline float bflo2f(unsigned int v) { return __uint_as_float(v << 16); }

// ---------------------------------------------------------------- K1: pad/transpose + weight prep
__global__ __launch_bounds__(1024) void pad_prep(const float* __restrict__ x,
                                                 const float* __restrict__ W_off,
                                                 const float* __restrict__ W_conv,
                                                 char* __restrict__ wsb) {
    unsigned short* xpb = (unsigned short*)(wsb + XPB_B);
    unsigned short* xpl = (unsigned short*)(wsb + XPL_B);
    int t = threadIdx.x;
    if (blockIdx.x >= 520) {   // ---- weight prep: 16 blocks x 3456 items
        unsigned short* Wb  = (unsigned short*)(wsb + WBB_B);
        unsigned short* Woh = (unsigned short*)(wsb + WOH_B);
        unsigned short* Wol = (unsigned short*)(wsb + WOL_B);
        int wb = blockIdx.x - 520;
        for (int ii = t; ii < 3456; ii += 1024) {
            int e = wb * 3456 + ii;
            if (e < 36864) {
                int j = e & 7, lane = (e >> 3) & 63, t2 = e >> 9;
                int ks = t2 % 36, nt = t2 / 36;
                int k = ks * 16 + ((lane >> 5) << 3) + j;
                int n = nt * 32 + (lane & 31);
                Wb[e] = f2bf(W_conv[(n * 64 + (k & 63)) * 9 + (k >> 6)]);
            } else {
                int e2 = e - 36864;     // W_off hi/lo frags, N=32 (18 used)
                int j = e2 & 7, lane = (e2 >> 3) & 63, ksg = e2 >> 9;
                int k = ksg * 16 + ((lane >> 5) << 3) + j;
                int c = k & 63, tap = k >> 6, n = lane & 31;
                float v = 0.f;
                if (n < 18) { int ko = (n < 9) ? 2 * n : 2 * (n - 9) + 1; v = W_off[(ko * 64 + c) * 9 + tap]; }
                unsigned short hi = f2bf(v);
                Woh[e2] = hi;
                Wol[e2] = f2bf(v - bfhi2f((unsigned int)hi << 16));
            }
        }
        return;
    }
    __shared__ float tile[64][129];
    int hp = blockIdx.x % 130, b = blockIdx.x / 130;
    int rowbase = ((b * 130 + hp) * 130) * 64;
    if (hp == 0 || hp == 129) {
        for (int i = t; i < 130 * 32; i += 1024) {
            ((unsigned*)(xpb + rowbase))[i] = 0u;
            ((unsigned*)(xpl + rowbase))[i] = 0u;
        }
        return;
    }
    int h = hp - 1;
    {
        int w = t & 127, cq = t >> 7;
#pragma unroll
        for (int cc = 0; cc < 8; cc++) {
            int c = cq + cc * 8;
            tile[c][w] = x[(((b * 64 + c) * 128) + h) * 128 + w];   // coalesced over w
        }
    }
    __syncthreads();
    {
        int c2 = (t & 31) * 2, wq = t >> 5;
        if (wq == 0) { ((unsigned*)(xpb + rowbase))[t & 31] = 0u; ((unsigned*)(xpl + rowbase))[t & 31] = 0u; }
        if (wq == 1) { ((unsigned*)(xpb + rowbase + 129 * 64))[t & 31] = 0u; ((unsigned*)(xpl + rowbase + 129 * 64))[t & 31] = 0u; }
#pragma unroll
        for (int w = wq; w < 128; w += 32) {
            float v0 = tile[c2][w], v1 = tile[c2 + 1][w];
            unsigned short h0 = f2bf(v0), h1 = f2bf(v1);
            unsigned short l0 = f2bf(v0 - bfhi2f((unsigned int)h0 << 16));
            unsigned short l1 = f2bf(v1 - bfhi2f((unsigned int)h1 << 16));
            int ad = (rowbase + (w + 1) * 64) / 2 + (t & 31);
            ((unsigned*)xpb)[ad] = (unsigned)h0 | ((unsigned)h1 << 16);
            ((unsigned*)xpl)[ad] = (unsigned)l0 | ((unsigned)l1 << 16);
        }
    }
}

// ---------------------------------------------------------------- K2: fused, 8 waves / 32 px
// LDS 37,120 B total (4 blocks/CU):
//   stage xh [0,13872) xl [13872,27744)  (P0-P1)
//   obuf [0,19456)                        (P2-P3a, after B2)
//   cdat: per-wave, wv*4640+3488, 36 x 32B {uint4 offs; float4 wt}  (P3b-P5, after B3b)
//   xs   [0,37120)                        (P5-P6; overwrites cdat tail in verified-safe order)
//   obuf2 [0,33792)                       (P7, after B6)
__global__ __launch_bounds__(512, 8) void deform_fused(const float* __restrict__ b_off,
                                                       float* __restrict__ out,
                                                       char* __restrict__ wsb) {
    const unsigned* xpbw = (const unsigned*)(wsb + XPB_B);
    const unsigned* xplw = (const unsigned*)(wsb + XPL_B);
    const short8* Woh = (const short8*)(wsb + WOH_B);
    const short8* Wol = (const short8*)(wsb + WOL_B);
    const short8* Wb  = (const short8*)(wsb + WBB_B);

    __shared__ __attribute__((aligned(16))) char smem[37120];
    unsigned short* xh = (unsigned short*)smem;              // stage hi
    unsigned short* xl = xh + 3 * K2_RS;                     // stage lo
    float* obuf = (float*)smem;                              // [8][32][19]
    unsigned short* xs = (unsigned short*)smem;              // [32][580]
    float* obuf2 = (float*)smem;                             // [8][32][33]

    int t = threadIdx.x;
    int lane = t & 63, wv = t >> 6;                          // wv 0..7
    int pixbase = blockIdx.x * 32;
    int w0 = pixbase & 127, h0 = (pixbase >> 7) & 127, bimg = pixbase >> 14;
    int m = lane & 31, half8 = (lane >> 5) << 3;

    // ---- P0: stage 3 rows x 34 cols x 64 ch hi/lo (dword = 2ch), fully coalesced
    for (int i = t; i < 3264; i += 512) {
        int row = i / 1088, rem = i - row * 1088;
        int wp = rem >> 5, cd = rem & 31;
        int g = ((bimg * 130 + h0 + row) * 130 + (w0 + wp)) * 32 + cd;
        int d = row * (K2_RS / 2) + wp * (K2_WS / 2) + cd;
        ((unsigned*)xh)[d] = xpbw[g];
        ((unsigned*)xl)[d] = xplw[g];
    }
    __syncthreads();                                         // B1

    // ---- P1: offset conv via split-bf16 MFMA, all 8 waves (ksg split 5,5,5,5,4,4,4,4)
    float16 acc1;
#pragma unroll
    for (int r = 0; r < 16; r++) acc1[r] = 0.f;
    {
        int ks0  = (wv < 4) ? wv * 5 : 20 + (wv - 4) * 4;
        int kcnt = (wv < 4) ? 5 : 4;
#pragma unroll
        for (int i = 0; i < 5; i++) {
            if (i < kcnt) {
                int ksg = ks0 + i;
                int tap = ksg >> 2;
                int c0 = ((ksg & 3) << 4) + half8;
                int ty = tap / 3, tx = tap - 3 * ty;
                int eb = ty * K2_RS + (m + tx) * K2_WS + c0;
                short4_t h0v = *(const short4_t*)(xh + eb);
                short4_t h1v = *(const short4_t*)(xh + eb + 4);
                short4_t l0v = *(const short4_t*)(xl + eb);
                short4_t l1v = *(const short4_t*)(xl + eb + 4);
                short8 ah = __builtin_shufflevector(h0v, h1v, 0, 1, 2, 3, 4, 5, 6, 7);
                short8 al = __builtin_shufflevector(l0v, l1v, 0, 1, 2, 3, 4, 5, 6, 7);
                short8 bh = Woh[ksg * 64 + lane];
                short8 bl = Wol[ksg * 64 + lane];
                acc1 = __builtin_amdgcn_mfma_f32_32x32x16_bf16(ah, bh, acc1, 0, 0, 0);
                acc1 = __builtin_amdgcn_mfma_f32_32x32x16_bf16(ah, bl, acc1, 0, 0, 0);
                acc1 = __builtin_amdgcn_mfma_f32_32x32x16_bf16(al, bh, acc1, 0, 0, 0);
            }
        }
    }
    __syncthreads();                                         // B2: stage reads done, obuf fresh
    // ---- P2: partials -> obuf[wv][row][n] (all 8 waves, n<18 used, stride 19)
    if (m < 18) {
#pragma unroll
        for (int r = 0; r < 16; r++) {
            int row = (r & 3) + 8 * (r >> 2) + 4 * (lane >> 5);
            obuf[(wv * 32 + row) * 19 + m] = acc1[r];
        }
    }
    __syncthreads();                                         // B3

    // ---- P3a: per-(pixel,tap) bilinear setup (exact fp32 decisions) -> registers
    bool act = (t < 288);
    unsigned rofs0 = 0, rofs1 = 0, rofs2 = 0, rofs3 = 0;
    float rg0 = 0.f, rg1 = 0.f, rg2 = 0.f, rg3 = 0.f;
    if (act) {
        int it = t;
        int p = (it * 7282) >> 16;              // /9
        int n = it - p * 9;
        float orow = b_off[2 * n], ocol = b_off[2 * n + 1];
#pragma unroll
        for (int kq = 0; kq < 8; kq++) {
            orow += obuf[(kq * 32 + p) * 19 + n];
            ocol += obuf[(kq * 32 + p) * 19 + 9 + n];
        }
        float pr = (float)(h0 + (n / 3)) + orow;
        float pc = (float)(w0 + p + (n % 3)) + ocol;
        float flr = floorf(pr), flc = floorf(pc);
        float qlt_r = fminf(fmaxf(flr, 0.f), 129.f);
        float qlt_c = fminf(fmaxf(flc, 0.f), 129.f);
        float qrb_r = fminf(fmaxf(flr + 1.f, 0.f), 129.f);
        float qrb_c = fminf(fmaxf(flc + 1.f, 0.f), 129.f);
        bool mr = (pr < 1.f) || (pr > 128.f);
        bool mc = (pc < 1.f) || (pc > 128.f);
        float pr2 = mr ? flr : pr; pr2 = fminf(fmaxf(pr2, 0.f), 129.f);
        float pc2 = mc ? flc : pc; pc2 = fminf(fmaxf(pc2, 0.f), 129.f);
        float wr_lt = 1.f + (qlt_r - pr2);
        float wr_rb = 1.f - (qrb_r - pr2);
        float wc_lt = 1.f + (qlt_c - pc2);
        float wc_rb = 1.f - (qrb_c - pc2);
        int ilt_r = (int)qlt_r, ilt_c = (int)qlt_c;
        int irb_r = (int)qrb_r, irb_c = (int)qrb_c;
        rg0 = wr_lt * wc_lt; rg1 = wr_rb * wc_rb;            // Gx, Gy
        rg2 = wr_lt * wc_rb; rg3 = wr_rb * wc_lt;            // Gz, Gw
        rofs0 = (unsigned)(ilt_r * 16640 + ilt_c * 128);     // LT
        rofs1 = (unsigned)(irb_r * 16640 + irb_c * 128);     // RB
        rofs2 = (unsigned)(ilt_r * 16640 + irb_c * 128);     // LB
        rofs3 = (unsigned)(irb_r * 16640 + ilt_c * 128);     // RT
    }
    __syncthreads();                                         // B3b: obuf reads done -> cdat may overwrite
    // ---- P3b: write cdat records into owning wave's xs-tail region
    if (act) {
        int it = t;
        int ww = (it * 7282) >> 18;             // /36  (it<288 so exact: 7282*288>>18 fits)
        int jj = it - ww * 36;
        char* rec = smem + ww * 4640 + 3488 + 32 * jj;
        *(uint4*)rec = make_uint4(rofs0, rofs1, rofs2, rofs3);
        *(float4*)(rec + 16) = make_float4(rg0, rg1, rg2, rg3);
    }
    __syncthreads();                                         // B4: cdat visible

    // ---- P5: gather, 8 waves x 36 items, fully unrolled; saddr loads, imm-offset ds_writes.
    // Reads of record j (iter floor(j/2)) strictly precede xs overwrites of its bytes (iters 13+).
    {
        int half = lane >> 5;
        unsigned cp4 = (unsigned)((lane & 31) * 4);
        const char* bp = (const char*)(wsb + XPB_B) + (size_t)bimg * (130 * 130 * 128);
        const char* crec = smem + wv * 4640 + 3488 + half * 32;
        char* xsb = (char*)smem;
        unsigned hb0 = (unsigned)(wv * 4640) + cp4 + (unsigned)(half * 128);
        unsigned hb8 = hb0 + (unsigned)(half * 8);
#pragma unroll
        for (int i = 0; i < 18; i++) {
            uint4  offs = *(const uint4*)(crec + 64 * i);
            float4 wt   = *(const float4*)(crec + 64 * i + 16);
            unsigned v0 = *(const unsigned*)(bp + (offs.x + cp4));
            unsigned v1 = *(const unsigned*)(bp + (offs.y + cp4));
            unsigned v2 = *(const unsigned*)(bp + (offs.z + cp4));
            unsigned v3 = *(const unsigned*)(bp + (offs.w + cp4));
            float lo = fmaf(wt.x, bflo2f(v0), fmaf(wt.y, bflo2f(v1), fmaf(wt.z, bflo2f(v2), wt.w * bflo2f(v3))));
            float hi = fmaf(wt.x, bfhi2f(v0), fmaf(wt.y, bfhi2f(v1), fmaf(wt.z, bfhi2f(v2), wt.w * bfhi2f(v3))));
            __hip_bfloat162 pk2 = __float22bfloat162_rn(make_float2(lo, hi));
            const int C = 256 * i + ((2 * i) / 9) * 8;       // compile-time
            unsigned base = (i == 4 || i == 13) ? hb8 : hb0; // compile-time select
            *(unsigned*)(xsb + base + C) = *(unsigned*)&pk2;
        }
    }
    __syncthreads();                                         // B5

    // ---- P6: contraction MFMA. wave: nt = N-tile (32 outs), kh = K-quarter (144)
    int nt = wv & 1, kh = wv >> 1;
    float16 acc;
#pragma unroll
    for (int r = 0; r < 16; r++) acc[r] = 0.f;
#pragma unroll
    for (int i2 = 0; i2 < 9; i2++) {
        int ksg = kh * 9 + i2;
        int baseE = m * XS_STRIDE + ksg * 16 + half8;
        short4_t a0 = *(const short4_t*)(xs + baseE);        // b64: stride 290dw -> 2-way only
        short4_t a1 = *(const short4_t*)(xs + baseE + 4);
        short8 af = __builtin_shufflevector(a0, a1, 0, 1, 2, 3, 4, 5, 6, 7);
        short8 bfv = Wb[(nt * 36 + ksg) * 64 + lane];        // coalesced 1KB, L2-resident
        acc = __builtin_amdgcn_mfma_f32_32x32x16_bf16(af, bfv, acc, 0, 0, 0);
    }
    __syncthreads();                                         // B6: all xs reads done -> obuf2 alias safe
    // ---- P7: each (kh,nt) wave writes its own obuf2 region; single barrier; add at store
#pragma unroll
    for (int r = 0; r < 16; r++) {
        int mrow = (r & 3) + 8 * (r >> 2) + 4 * (lane >> 5);
        obuf2[(kh * 2 + nt) * 1056 + mrow * 33 + m] = acc[r];
    }
    __syncthreads();                                         // B7
#pragma unroll
    for (int i = 0; i < 4; i++) {
        int lin = i * 512 + t;
        int o = lin >> 5, p = lin & 31;
        int oi = (o >> 5) * 1056 + p * 33 + (o & 31);
        float v = (obuf2[oi] + obuf2[oi + 2112])
                + (obuf2[oi + 4224] + obuf2[oi + 6336]);     // kh0..kh3 partials
        out[((bimg * 64 + o) << 14) + (h0 << 7) + w0 + p] = v;
    }
}

// ---------------------------------------------------------------- launch
extern "C" void kernel_launch(void* const* d_in, const int* in_sizes, int n_in,
                              void* d_out, int out_size, void* d_ws, size_t ws_size,
                              hipStream_t stream) {
    const float* x      = (const float*)d_in[0];
    const float* W_off  = (const float*)d_in[1];
    const float* b_off  = (const float*)d_in[2];
    const float* W_conv = (const float*)d_in[3];
    char* wsb  = (char*)d_ws;            // needs 17,453,056 B
    float* out = (float*)d_out;

    hipLaunchKernelGGL(pad_prep, dim3(536), dim3(1024), 0, stream, x, W_off, W_conv, wsb);
    hipLaunchKernelGGL(deform_fused, dim3(NPIX / 32), dim3(512), 0, stream, b_off, out, wsb);
}

// Round 4
// 110.910 us; speedup vs baseline: 1.1884x; 1.0202x over previous
//
#include <hip/hip_runtime.h>
#include <hip/hip_bf16.h>
#include <math.h>

// DeformConv2D MI355X: b=4,c=64,H=W=128,KS=3,N=9 -> out[b,o,h,w] = sum_{c,n} W[o,c,n]*bilin(xpad,p)
// R12: P5 gather restructured: 8-lane groups x dwordx4 loads (8 items/wave-iter, 4.5 iters vs 18),
//      packed float2 fma (v_pk_fma_f32, same nesting -> bit-identical), b64 ds_writes with
//      bank-rotation sub=(lane+g)&7 (provably conflict-free). P0 staging vectorized (uint4 loads,
//      b64 LDS writes). cdat-in-xs-tail aliasing re-verified for new item order (records j read at
//      iter floor(j/8); tail bytes only overwritten at iters 3-4 after owning reads; same-wave DS
//      ops program-ordered). Numerics bit-identical (absmax 0.03125). LDS 37,120 B, 4 blocks/CU.

typedef __attribute__((ext_vector_type(8)))  short short8;
typedef __attribute__((ext_vector_type(4)))  short short4_t;
typedef __attribute__((ext_vector_type(16))) float float16;
typedef __attribute__((ext_vector_type(2)))  float floatx2;
typedef __attribute__((ext_vector_type(4)))  unsigned uintx4;
typedef __attribute__((ext_vector_type(2)))  unsigned uintx2;

#define NPIX 65536
#define XS_STRIDE 580   // xs leading dim (bf16): dword stride 290 = 2 mod 32 -> 2-way (free)
#define K2_WS 68        // stage wp stride (64ch + 4 pad)
#define K2_RS 2312      // stage row stride (34*68)

// workspace layout (byte offsets)
#define XPB_B   0u           // bf16 hi padded NHWC x : 8,652,800 B
#define XPL_B   8652800u     // bf16 lo residual      : 8,652,800 B
#define WBB_B   17305600u    // W_conv bf16 MFMA B-frags: 73,728 B
#define WOH_B   17379328u    // W_off hi B-frags      : 36,864 B
#define WOL_B   17416192u    // W_off lo B-frags      : 36,864 B (end 17,453,056)

__device__ inline unsigned short f2bf(float f) {
    unsigned int u = __float_as_uint(f);
    u += 0x7fffu + ((u >> 16) & 1u);           // RNE
    return (unsigned short)(u >> 16);
}
__device__ inline float bfhi2f(unsigned int v) { return __uint_as_float(v & 0xffff0000u); }
__device__ inline float bflo2f(unsigned int v) { return __uint_as_float(v << 16); }
__device__ inline floatx2 up2(unsigned int v) {
    floatx2 r; r.x = bflo2f(v); r.y = bfhi2f(v); return r;
}

// ---------------------------------------------------------------- K1: pad/transpose + weight prep
__global__ __launch_bounds__(1024) void pad_prep(const float* __restrict__ x,
                                                 const float* __restrict__ W_off,
                                                 const float* __restrict__ W_conv,
                                                 char* __restrict__ wsb) {
    unsigned short* xpb = (unsigned short*)(wsb + XPB_B);
    unsigned short* xpl = (unsigned short*)(wsb + XPL_B);
    int t = threadIdx.x;
    if (blockIdx.x >= 520) {   // ---- weight prep: 16 blocks x 3456 items
        unsigned short* Wb  = (unsigned short*)(wsb + WBB_B);
        unsigned short* Woh = (unsigned short*)(wsb + WOH_B);
        unsigned short* Wol = (unsigned short*)(wsb + WOL_B);
        int wb = blockIdx.x - 520;
        for (int ii = t; ii < 3456; ii += 1024) {
            int e = wb * 3456 + ii;
            if (e < 36864) {
                int j = e & 7, lane = (e >> 3) & 63, t2 = e >> 9;
                int ks = t2 % 36, nt = t2 / 36;
                int k = ks * 16 + ((lane >> 5) << 3) + j;
                int n = nt * 32 + (lane & 31);
                Wb[e] = f2bf(W_conv[(n * 64 + (k & 63)) * 9 + (k >> 6)]);
            } else {
                int e2 = e - 36864;     // W_off hi/lo frags, N=32 (18 used)
                int j = e2 & 7, lane = (e2 >> 3) & 63, ksg = e2 >> 9;
                int k = ksg * 16 + ((lane >> 5) << 3) + j;
                int c = k & 63, tap = k >> 6, n = lane & 31;
                float v = 0.f;
                if (n < 18) { int ko = (n < 9) ? 2 * n : 2 * (n - 9) + 1; v = W_off[(ko * 64 + c) * 9 + tap]; }
                unsigned short hi = f2bf(v);
                Woh[e2] = hi;
                Wol[e2] = f2bf(v - bfhi2f((unsigned int)hi << 16));
            }
        }
        return;
    }
    __shared__ float tile[64][129];
    int hp = blockIdx.x % 130, b = blockIdx.x / 130;
    int rowbase = ((b * 130 + hp) * 130) * 64;
    if (hp == 0 || hp == 129) {
        for (int i = t; i < 130 * 32; i += 1024) {
            ((unsigned*)(xpb + rowbase))[i] = 0u;
            ((unsigned*)(xpl + rowbase))[i] = 0u;
        }
        return;
    }
    int h = hp - 1;
    {
        int w = t & 127, cq = t >> 7;
#pragma unroll
        for (int cc = 0; cc < 8; cc++) {
            int c = cq + cc * 8;
            tile[c][w] = x[(((b * 64 + c) * 128) + h) * 128 + w];   // coalesced over w
        }
    }
    __syncthreads();
    {
        int c2 = (t & 31) * 2, wq = t >> 5;
        if (wq == 0) { ((unsigned*)(xpb + rowbase))[t & 31] = 0u; ((unsigned*)(xpl + rowbase))[t & 31] = 0u; }
        if (wq == 1) { ((unsigned*)(xpb + rowbase + 129 * 64))[t & 31] = 0u; ((unsigned*)(xpl + rowbase + 129 * 64))[t & 31] = 0u; }
#pragma unroll
        for (int w = wq; w < 128; w += 32) {
            float v0 = tile[c2][w], v1 = tile[c2 + 1][w];
            unsigned short h0 = f2bf(v0), h1 = f2bf(v1);
            unsigned short l0 = f2bf(v0 - bfhi2f((unsigned int)h0 << 16));
            unsigned short l1 = f2bf(v1 - bfhi2f((unsigned int)h1 << 16));
            int ad = (rowbase + (w + 1) * 64) / 2 + (t & 31);
            ((unsigned*)xpb)[ad] = (unsigned)h0 | ((unsigned)h1 << 16);
            ((unsigned*)xpl)[ad] = (unsigned)l0 | ((unsigned)l1 << 16);
        }
    }
}

// ---------------------------------------------------------------- K2: fused, 8 waves / 32 px
// LDS 37,120 B total (4 blocks/CU):
//   stage xh [0,13872) xl [13872,27744)  (P0-P1)
//   obuf [0,19456)                        (P2-P3a, after B2)
//   cdat: per-wave, wv*4640+3488, 36 x 32B {uint4 offs; float4 wt}  (P3b-P5, after B3b)
//   xs   [0,37120)                        (P5-P6; overwrites cdat tail in verified-safe order)
//   obuf2 [0,33792)                       (P7, after B6)
__global__ __launch_bounds__(512, 8) void deform_fused(const float* __restrict__ b_off,
                                                       float* __restrict__ out,
                                                       char* __restrict__ wsb) {
    const uintx4* xpb4 = (const uintx4*)(wsb + XPB_B);
    const uintx4* xpl4 = (const uintx4*)(wsb + XPL_B);
    const short8* Woh = (const short8*)(wsb + WOH_B);
    const short8* Wol = (const short8*)(wsb + WOL_B);
    const short8* Wb  = (const short8*)(wsb + WBB_B);

    __shared__ __attribute__((aligned(16))) char smem[37120];
    unsigned short* xh = (unsigned short*)smem;              // stage hi
    unsigned short* xl = xh + 3 * K2_RS;                     // stage lo
    float* obuf = (float*)smem;                              // [8][32][19]
    unsigned short* xs = (unsigned short*)smem;              // [32][580]
    float* obuf2 = (float*)smem;                             // [8][32][33]

    int t = threadIdx.x;
    int lane = t & 63, wv = t >> 6;                          // wv 0..7
    int pixbase = blockIdx.x * 32;
    int w0 = pixbase & 127, h0 = (pixbase >> 7) & 127, bimg = pixbase >> 14;
    int m = lane & 31, half8 = (lane >> 5) << 3;

    // ---- P0: stage 3 rows x 34 cols x 64 ch hi/lo; uint4 loads, b64 LDS writes.
    // 816 quad-items = 3 rows x 34 wp x 8 quads.
#pragma unroll
    for (int s = 0; s < 2; s++) {
        int i = t + s * 512;
        if (s == 0 || t < 304) {
            int row = i / 272, rem = i - row * 272;
            int wp = rem >> 3, q = rem & 7;
            int gq = ((bimg * 130 + h0 + row) * 130 + (w0 + wp)) * 8 + q;   // uint4 index
            uintx4 vh = xpb4[gq];
            uintx4 vl = xpl4[gq];
            int d = row * (K2_RS / 2) + wp * (K2_WS / 2) + q * 4;           // dword index (even)
            uintx2 h01; h01.x = vh.x; h01.y = vh.y;
            uintx2 h23; h23.x = vh.z; h23.y = vh.w;
            uintx2 l01; l01.x = vl.x; l01.y = vl.y;
            uintx2 l23; l23.x = vl.z; l23.y = vl.w;
            *(uintx2*)((unsigned*)xh + d)     = h01;
            *(uintx2*)((unsigned*)xh + d + 2) = h23;
            *(uintx2*)((unsigned*)xl + d)     = l01;
            *(uintx2*)((unsigned*)xl + d + 2) = l23;
        }
    }
    __syncthreads();                                         // B1

    // ---- P1: offset conv via split-bf16 MFMA, all 8 waves (ksg split 5,5,5,5,4,4,4,4)
    float16 acc1;
#pragma unroll
    for (int r = 0; r < 16; r++) acc1[r] = 0.f;
    {
        int ks0  = (wv < 4) ? wv * 5 : 20 + (wv - 4) * 4;
        int kcnt = (wv < 4) ? 5 : 4;
#pragma unroll
        for (int i = 0; i < 5; i++) {
            if (i < kcnt) {
                int ksg = ks0 + i;
                int tap = ksg >> 2;
                int c0 = ((ksg & 3) << 4) + half8;
                int ty = tap / 3, tx = tap - 3 * ty;
                int eb = ty * K2_RS + (m + tx) * K2_WS + c0;
                short4_t h0v = *(const short4_t*)(xh + eb);
                short4_t h1v = *(const short4_t*)(xh + eb + 4);
                short4_t l0v = *(const short4_t*)(xl + eb);
                short4_t l1v = *(const short4_t*)(xl + eb + 4);
                short8 ah = __builtin_shufflevector(h0v, h1v, 0, 1, 2, 3, 4, 5, 6, 7);
                short8 al = __builtin_shufflevector(l0v, l1v, 0, 1, 2, 3, 4, 5, 6, 7);
                short8 bh = Woh[ksg * 64 + lane];
                short8 bl = Wol[ksg * 64 + lane];
                acc1 = __builtin_amdgcn_mfma_f32_32x32x16_bf16(ah, bh, acc1, 0, 0, 0);
                acc1 = __builtin_amdgcn_mfma_f32_32x32x16_bf16(ah, bl, acc1, 0, 0, 0);
                acc1 = __builtin_amdgcn_mfma_f32_32x32x16_bf16(al, bh, acc1, 0, 0, 0);
            }
        }
    }
    __syncthreads();                                         // B2: stage reads done, obuf fresh
    // ---- P2: partials -> obuf[wv][row][n] (all 8 waves, n<18 used, stride 19)
    if (m < 18) {
#pragma unroll
        for (int r = 0; r < 16; r++) {
            int row = (r & 3) + 8 * (r >> 2) + 4 * (lane >> 5);
            obuf[(wv * 32 + row) * 19 + m] = acc1[r];
        }
    }
    __syncthreads();                                         // B3

    // ---- P3a: per-(pixel,tap) bilinear setup (exact fp32 decisions) -> registers
    bool act = (t < 288);
    unsigned rofs0 = 0, rofs1 = 0, rofs2 = 0, rofs3 = 0;
    float rg0 = 0.f, rg1 = 0.f, rg2 = 0.f, rg3 = 0.f;
    if (act) {
        int it = t;
        int p = (it * 7282) >> 16;              // /9
        int n = it - p * 9;
        float orow = b_off[2 * n], ocol = b_off[2 * n + 1];
#pragma unroll
        for (int kq = 0; kq < 8; kq++) {
            orow += obuf[(kq * 32 + p) * 19 + n];
            ocol += obuf[(kq * 32 + p) * 19 + 9 + n];
        }
        float pr = (float)(h0 + (n / 3)) + orow;
        float pc = (float)(w0 + p + (n % 3)) + ocol;
        float flr = floorf(pr), flc = floorf(pc);
        float qlt_r = fminf(fmaxf(flr, 0.f), 129.f);
        float qlt_c = fminf(fmaxf(flc, 0.f), 129.f);
        float qrb_r = fminf(fmaxf(flr + 1.f, 0.f), 129.f);
        float qrb_c = fminf(fmaxf(flc + 1.f, 0.f), 129.f);
        bool mr = (pr < 1.f) || (pr > 128.f);
        bool mc = (pc < 1.f) || (pc > 128.f);
        float pr2 = mr ? flr : pr; pr2 = fminf(fmaxf(pr2, 0.f), 129.f);
        float pc2 = mc ? flc : pc; pc2 = fminf(fmaxf(pc2, 0.f), 129.f);
        float wr_lt = 1.f + (qlt_r - pr2);
        float wr_rb = 1.f - (qrb_r - pr2);
        float wc_lt = 1.f + (qlt_c - pc2);
        float wc_rb = 1.f - (qrb_c - pc2);
        int ilt_r = (int)qlt_r, ilt_c = (int)qlt_c;
        int irb_r = (int)qrb_r, irb_c = (int)qrb_c;
        rg0 = wr_lt * wc_lt; rg1 = wr_rb * wc_rb;            // Gx, Gy
        rg2 = wr_lt * wc_rb; rg3 = wr_rb * wc_lt;            // Gz, Gw
        rofs0 = (unsigned)(ilt_r * 16640 + ilt_c * 128);     // LT
        rofs1 = (unsigned)(irb_r * 16640 + irb_c * 128);     // RB
        rofs2 = (unsigned)(ilt_r * 16640 + irb_c * 128);     // LB
        rofs3 = (unsigned)(irb_r * 16640 + ilt_c * 128);     // RT
    }
    __syncthreads();                                         // B3b: obuf reads done -> cdat may overwrite
    // ---- P3b: write cdat records into owning wave's xs-tail region
    if (act) {
        int it = t;
        int ww = (it * 7282) >> 18;             // /36
        int jj = it - ww * 36;
        char* rec = smem + ww * 4640 + 3488 + 32 * jj;
        *(uint4*)rec = make_uint4(rofs0, rofs1, rofs2, rofs3);
        *(float4*)(rec + 16) = make_float4(rg0, rg1, rg2, rg3);
    }
    __syncthreads();                                         // B4: cdat visible

    // ---- P5: gather, 8-lane groups, 8 items/wave-iter (4 full iters + 1 half).
    // Lane (g,sub_raw) handles dwords 4*rot..4*rot+3 of item j=8i+g, rot=(sub_raw+g)&7
    // (rotation makes b64 write banks provably distinct). dwordx4 loads; packed f32 fma.
    {
        int g = lane >> 3;
        unsigned s16 = (unsigned)((((lane & 7) + g) & 7) * 16);
        const char* bp = (const char*)(wsb + XPB_B) + (size_t)bimg * (130 * 130 * 128);
        const char* crec = smem + wv * 4640 + 3488 + 32 * g;
        unsigned wvb = (unsigned)(wv * 4640);
        char* xsb = (char*)smem;
#pragma unroll
        for (int i = 0; i < 5; i++) {
            if (i < 4 || g < 4) {
                uintx4 offs = *(const uintx4*)(crec + 256 * i);
                float4 wt   = *(const float4*)(crec + 256 * i + 16);
                uintx4 v0 = *(const uintx4*)(bp + (offs.x + s16));
                uintx4 v1 = *(const uintx4*)(bp + (offs.y + s16));
                uintx4 v2 = *(const uintx4*)(bp + (offs.z + s16));
                uintx4 v3 = *(const uintx4*)(bp + (offs.w + s16));
                floatx2 wx; wx.x = wt.x; wx.y = wt.x;
                floatx2 wy; wy.x = wt.y; wy.y = wt.y;
                floatx2 wz; wz.x = wt.z; wz.y = wt.z;
                floatx2 wwv; wwv.x = wt.w; wwv.y = wt.w;
                int jj = 8 * i + g;
                unsigned q9 = (unsigned)((jj * 7282) >> 16);
                unsigned wa = wvb + ((unsigned)jj << 7) + (q9 << 3) + s16;
                unsigned r0, r1, r2, r3;
                {
                    floatx2 f = __builtin_elementwise_fma(wx, up2(v0.x),
                                 __builtin_elementwise_fma(wy, up2(v1.x),
                                  __builtin_elementwise_fma(wz, up2(v2.x), wwv * up2(v3.x))));
                    __hip_bfloat162 pk2 = __float22bfloat162_rn(make_float2(f.x, f.y));
                    r0 = *(unsigned*)&pk2;
                }
                {
                    floatx2 f = __builtin_elementwise_fma(wx, up2(v0.y),
                                 __builtin_elementwise_fma(wy, up2(v1.y),
                                  __builtin_elementwise_fma(wz, up2(v2.y), wwv * up2(v3.y))));
                    __hip_bfloat162 pk2 = __float22bfloat162_rn(make_float2(f.x, f.y));
                    r1 = *(unsigned*)&pk2;
                }
                {
                    floatx2 f = __builtin_elementwise_fma(wx, up2(v0.z),
                                 __builtin_elementwise_fma(wy, up2(v1.z),
                                  __builtin_elementwise_fma(wz, up2(v2.z), wwv * up2(v3.z))));
                    __hip_bfloat162 pk2 = __float22bfloat162_rn(make_float2(f.x, f.y));
                    r2 = *(unsigned*)&pk2;
                }
                {
                    floatx2 f = __builtin_elementwise_fma(wx, up2(v0.w),
                                 __builtin_elementwise_fma(wy, up2(v1.w),
                                  __builtin_elementwise_fma(wz, up2(v2.w), wwv * up2(v3.w))));
                    __hip_bfloat162 pk2 = __float22bfloat162_rn(make_float2(f.x, f.y));
                    r3 = *(unsigned*)&pk2;
                }
                uintx2 w01; w01.x = r0; w01.y = r1;
                uintx2 w23; w23.x = r2; w23.y = r3;
                *(uintx2*)(xsb + wa)     = w01;
                *(uintx2*)(xsb + wa + 8) = w23;
            }
        }
    }
    __syncthreads();                                         // B5

    // ---- P6: contraction MFMA. wave: nt = N-tile (32 outs), kh = K-quarter (144)
    int nt = wv & 1, kh = wv >> 1;
    float16 acc;
#pragma unroll
    for (int r = 0; r < 16; r++) acc[r] = 0.f;
#pragma unroll
    for (int i2 = 0; i2 < 9; i2++) {
        int ksg = kh * 9 + i2;
        int baseE = m * XS_STRIDE + ksg * 16 + half8;
        short4_t a0 = *(const short4_t*)(xs + baseE);        // b64: stride 290dw -> 2-way only
        short4_t a1 = *(const short4_t*)(xs + baseE + 4);
        short8 af = __builtin_shufflevector(a0, a1, 0, 1, 2, 3, 4, 5, 6, 7);
        short8 bfv = Wb[(nt * 36 + ksg) * 64 + lane];        // coalesced 1KB, L2-resident
        acc = __builtin_amdgcn_mfma_f32_32x32x16_bf16(af, bfv, acc, 0, 0, 0);
    }
    __syncthreads();                                         // B6: all xs reads done -> obuf2 alias safe
    // ---- P7: each (kh,nt) wave writes its own obuf2 region; single barrier; add at store
#pragma unroll
    for (int r = 0; r < 16; r++) {
        int mrow = (r & 3) + 8 * (r >> 2) + 4 * (lane >> 5);
        obuf2[(kh * 2 + nt) * 1056 + mrow * 33 + m] = acc[r];
    }
    __syncthreads();                                         // B7
#pragma unroll
    for (int i = 0; i < 4; i++) {
        int lin = i * 512 + t;
        int o = lin >> 5, p = lin & 31;
        int oi = (o >> 5) * 1056 + p * 33 + (o & 31);
        float v = (obuf2[oi] + obuf2[oi + 2112])
                + (obuf2[oi + 4224] + obuf2[oi + 6336]);     // kh0..kh3 partials
        out[((bimg * 64 + o) << 14) + (h0 << 7) + w0 + p] = v;
    }
}

// ---------------------------------------------------------------- launch
extern "C" void kernel_launch(void* const* d_in, const int* in_sizes, int n_in,
                              void* d_out, int out_size, void* d_ws, size_t ws_size,
                              hipStream_t stream) {
    const float* x      = (const float*)d_in[0];
    const float* W_off  = (const float*)d_in[1];
    const float* b_off  = (const float*)d_in[2];
    const float* W_conv = (const float*)d_in[3];
    char* wsb  = (char*)d_ws;            // needs 17,453,056 B
    float* out = (float*)d_out;

    hipLaunchKernelGGL(pad_prep, dim3(536), dim3(1024), 0, stream, x, W_off, W_conv, wsb);
    hipLaunchKernelGGL(deform_fused, dim3(NPIX / 32), dim3(512), 0, stream, b_off, out, wsb);
}